// Round 3
// baseline (228.788 us; speedup 1.0000x reference)
//
#include <hip/hip_runtime.h>
#include <math.h>

#define N_VEC 65536
#define D 64
#define K 1024
#define VQ_EPS 1e-10f

typedef __attribute__((ext_vector_type(8))) short s16x8;   // 8 bf16 = 4 VGPR
typedef __attribute__((ext_vector_type(4))) float f32x4;   // MFMA acc

#define MFMA(a, b, c) __builtin_amdgcn_mfma_f32_16x16x32_bf16((a), (b), (c), 0, 0, 0)

__device__ __forceinline__ unsigned short bf16_rne(float f) {
    unsigned u = __float_as_uint(f);
    u += 0x7fff + ((u >> 16) & 1);
    return (unsigned short)(u >> 16);
}
__device__ __forceinline__ float bf16_f32(unsigned short h) {
    return __uint_as_float(((unsigned)h) << 16);
}

// ---------------------------------------------------------------------------
// Kernel A: pack embeddings to bf16 hi|lo ([code][128] ushort), fp32 norms,
// zero counts + done flag. 1024 threads total.
// ---------------------------------------------------------------------------
__global__ void pack_e_kernel(const float* __restrict__ emb,
                              unsigned short* __restrict__ ep,
                              float* __restrict__ enorm,
                              int* __restrict__ counts,
                              int* __restrict__ done) {
    int k = blockIdx.x * 256 + threadIdx.x;
    const float* row = emb + (size_t)k * D;
    unsigned short* orow = ep + ((size_t)k << 7);
    float nrm = 0.f;
#pragma unroll
    for (int j = 0; j < D; j += 4) {
        float4 v = *reinterpret_cast<const float4*>(row + j);
        nrm += v.x * v.x + v.y * v.y + v.z * v.z + v.w * v.w;
        float f[4] = {v.x, v.y, v.z, v.w};
#pragma unroll
        for (int i = 0; i < 4; ++i) {
            unsigned short h = bf16_rne(f[i]);
            orow[j + i]      = h;
            orow[64 + j + i] = bf16_rne(f[i] - bf16_f32(h));
        }
    }
    enorm[k] = nrm;
    counts[k] = 0;
    if (k == 0) *done = 0;
}

// ---------------------------------------------------------------------------
// Kernel B: MFMA VQ. Block = 256 thr = 4 waves, all sharing 64 vectors.
// Wave w handles code quarter w of each 64-code tile; ct loops 16 tiles.
// A-frags (x as bf16 hi/lo) live in VGPRs for the whole kernel; B-frags
// stream from L2-resident packed codebook. No LDS in the hot loop.
// dot = xh.eh + xh.el + xl.eh  (3-term split ~ fp32 precision; lo.lo ~3e-5).
// dist = ||e||^2 - 2 dot (row-constant ||x||^2 dropped; argmin unchanged).
// C-layout (m89-verified): col(code)=lane&15, row(vec)=(lane>>4)*4+reg.
// Last block (ticket) computes perplexity from counts.
// ---------------------------------------------------------------------------
__global__ void __launch_bounds__(256, 3)
vq_kernel(const float* __restrict__ x,
          const float* __restrict__ emb,
          const unsigned short* __restrict__ ep,
          const float* __restrict__ enormp,
          int* __restrict__ counts,
          int* __restrict__ done,
          float* __restrict__ out) {
    const int t    = threadIdx.x;
    const int w    = t >> 6;          // wave id (code quarter)
    const int lane = t & 63;
    const int q    = lane >> 4;       // k-subblock (8 elems)
    const int c    = lane & 15;       // column: vec-row for A, code for B/C
    const int vb   = blockIdx.x * 64;

    // ---- load x tile, convert to bf16 hi/lo A-fragments (in VGPRs) ----
    // A-frag layout: A[m=lane&15][k=(lane>>4)*8 + j]
    s16x8 Ah[4][2], Al[4][2];
#pragma unroll
    for (int mt = 0; mt < 4; ++mt) {
        const float* xr = x + (size_t)(vb + mt * 16 + c) * D + q * 8;
#pragma unroll
        for (int h = 0; h < 2; ++h) {
            float4 u0 = *reinterpret_cast<const float4*>(xr + h * 32);
            float4 u1 = *reinterpret_cast<const float4*>(xr + h * 32 + 4);
            float f[8] = {u0.x, u0.y, u0.z, u0.w, u1.x, u1.y, u1.z, u1.w};
            s16x8 hi, lo;
#pragma unroll
            for (int j = 0; j < 8; ++j) {
                unsigned short hb = bf16_rne(f[j]);
                hi[j] = (short)hb;
                lo[j] = (short)bf16_rne(f[j] - bf16_f32(hb));
            }
            Ah[mt][h] = hi;
            Al[mt][h] = lo;
        }
    }

    float best[16];
    int   bk_[16];
#pragma unroll
    for (int s = 0; s < 16; ++s) { best[s] = 3.4e38f; bk_[s] = 0; }

    // ---- B prefetch pipeline over 16 code-tiles ----
    s16x8 bh0, bh1, bl0, bl1;
    float en0;
    {
        int code = w * 16 + c;  // ct = 0
        const unsigned short* p = ep + ((size_t)code << 7) + (q << 3);
        bh0 = *reinterpret_cast<const s16x8*>(p);
        bh1 = *reinterpret_cast<const s16x8*>(p + 32);
        bl0 = *reinterpret_cast<const s16x8*>(p + 64);
        bl1 = *reinterpret_cast<const s16x8*>(p + 96);
        en0 = enormp[code];
    }

    for (int ct = 0; ct < 16; ++ct) {
        // prefetch next tile (clamped; ct=15's prefetch is discarded)
        int ctn = ct + 1 < 16 ? ct + 1 : 15;
        int ncode = ctn * 64 + w * 16 + c;
        const unsigned short* np = ep + ((size_t)ncode << 7) + (q << 3);
        s16x8 nh0 = *reinterpret_cast<const s16x8*>(np);
        s16x8 nh1 = *reinterpret_cast<const s16x8*>(np + 32);
        s16x8 nl0 = *reinterpret_cast<const s16x8*>(np + 64);
        s16x8 nl1 = *reinterpret_cast<const s16x8*>(np + 96);
        float nen = enormp[ncode];

        f32x4 acc[4];
#pragma unroll
        for (int mt = 0; mt < 4; ++mt) acc[mt] = (f32x4){0.f, 0.f, 0.f, 0.f};

#pragma unroll
        for (int mt = 0; mt < 4; ++mt) acc[mt] = MFMA(Ah[mt][0], bh0, acc[mt]);
#pragma unroll
        for (int mt = 0; mt < 4; ++mt) acc[mt] = MFMA(Ah[mt][1], bh1, acc[mt]);
#pragma unroll
        for (int mt = 0; mt < 4; ++mt) acc[mt] = MFMA(Ah[mt][0], bl0, acc[mt]);
#pragma unroll
        for (int mt = 0; mt < 4; ++mt) acc[mt] = MFMA(Ah[mt][1], bl1, acc[mt]);
#pragma unroll
        for (int mt = 0; mt < 4; ++mt) acc[mt] = MFMA(Al[mt][0], bh0, acc[mt]);
#pragma unroll
        for (int mt = 0; mt < 4; ++mt) acc[mt] = MFMA(Al[mt][1], bh1, acc[mt]);

        // epilogue: this lane's column code (same for all 16 slots)
        int codeL = ct * 64 + w * 16 + c;
#pragma unroll
        for (int mt = 0; mt < 4; ++mt)
#pragma unroll
            for (int r = 0; r < 4; ++r) {
                float dist = fmaf(-2.f, acc[mt][r], en0);
                int s = mt * 4 + r;
                if (dist < best[s]) { best[s] = dist; bk_[s] = codeL; }
            }

        bh0 = nh0; bh1 = nh1; bl0 = nl0; bl1 = nl1; en0 = nen;
    }

    // ---- reduce over 16 columns within wave (lexicographic: dist, index) ----
#pragma unroll
    for (int m = 1; m <= 8; m <<= 1)
#pragma unroll
        for (int s = 0; s < 16; ++s) {
            float ob = __shfl_xor(best[s], m, 64);
            int   ok = __shfl_xor(bk_[s], m, 64);
            if (ob < best[s] || (ob == best[s] && ok < bk_[s])) {
                best[s] = ob; bk_[s] = ok;
            }
        }

    __shared__ float rb[4][64];
    __shared__ int   rk[4][64];
    __shared__ int   bks[64];
    __shared__ int   islast;
    __shared__ float wsum[4];

    if (c == 0) {
#pragma unroll
        for (int mt = 0; mt < 4; ++mt)
#pragma unroll
            for (int r = 0; r < 4; ++r) {
                int vl = mt * 16 + q * 4 + r;
                rb[w][vl] = best[mt * 4 + r];
                rk[w][vl] = bk_[mt * 4 + r];
            }
    }
    __syncthreads();

    // ---- combine the 4 waves' code-quarters; counts atomics ----
    if (t < 64) {
        float b = rb[0][t]; int kk = rk[0][t];
#pragma unroll
        for (int ww = 1; ww < 4; ++ww) {
            float ob = rb[ww][t]; int ok = rk[ww][t];
            if (ob < b || (ob == b && ok < kk)) { b = ob; kk = ok; }
        }
        bks[t] = kk;
        atomicAdd(&counts[kk], 1);
    }
    __threadfence();
    __syncthreads();

    // ---- gather winning embedding rows -> out (exact fp32 copies) ----
    {
        int vec = t >> 2, part = t & 3;
        int kk = bks[vec];
        const float4* src = reinterpret_cast<const float4*>(emb + (size_t)kk * D + part * 16);
        float4* dst = reinterpret_cast<float4*>(out + (size_t)(vb + vec) * D + part * 16);
#pragma unroll
        for (int i = 0; i < 4; ++i) dst[i] = src[i];
    }

    // ---- ticket: last block computes perplexity ----
    if (t == 0) islast = (atomicAdd(done, 1) == (int)gridDim.x - 1);
    __syncthreads();
    if (islast) {
        __threadfence();
        float s = 0.f;
#pragma unroll
        for (int i = 0; i < 4; ++i) {
            int cnt = atomicAdd(&counts[t + i * 256], 0);  // coherent read
            float p = (float)cnt * (1.0f / (float)N_VEC);
            s += p * logf(p + VQ_EPS);
        }
#pragma unroll
        for (int m = 1; m < 64; m <<= 1) s += __shfl_xor(s, m, 64);
        if ((t & 63) == 0) wsum[t >> 6] = s;
        __syncthreads();
        if (t == 0) out[(size_t)N_VEC * D] = expf(-(wsum[0] + wsum[1] + wsum[2] + wsum[3]));
    }
}

// ---------------------------------------------------------------------------
extern "C" void kernel_launch(void* const* d_in, const int* in_sizes, int n_in,
                              void* d_out, int out_size, void* d_ws, size_t ws_size,
                              hipStream_t stream) {
    const float* x   = (const float*)d_in[0];   // [65536, 64] fp32
    const float* emb = (const float*)d_in[1];   // [1024, 64] fp32
    float* out = (float*)d_out;                 // 4194304 quantized + 1 perplexity

    unsigned short* ep = (unsigned short*)d_ws;                        // 256 KB
    float* enorm  = (float*)((char*)d_ws + (size_t)K * 128 * 2);       // 4 KB
    int*   counts = (int*)((char*)enorm + K * sizeof(float));          // 4 KB
    int*   done   = (int*)((char*)counts + K * sizeof(int));           // 4 B

    pack_e_kernel<<<K / 256, 256, 0, stream>>>(emb, ep, enorm, counts, done);
    vq_kernel<<<N_VEC / 64, 256, 0, stream>>>(x, emb, ep, enorm, counts, done, out);
}

// Round 6
// 162.086 us; speedup vs baseline: 1.4115x; 1.4115x over previous
//
#include <hip/hip_runtime.h>
#include <math.h>

#define N_VEC 65536
#define D 64
#define K 1024
#define VQ_EPS 1e-10f

typedef __attribute__((ext_vector_type(8))) short s16x8;   // 8 bf16 = 4 VGPR
typedef __attribute__((ext_vector_type(4))) float f32x4;   // MFMA acc

#define MFMA(a, b, c) __builtin_amdgcn_mfma_f32_16x16x32_bf16((a), (b), (c), 0, 0, 0)

__device__ __forceinline__ unsigned short bf16_rne(float f) {
    unsigned u = __float_as_uint(f);
    u += 0x7fff + ((u >> 16) & 1);
    return (unsigned short)(u >> 16);
}
__device__ __forceinline__ float bf16_f32(unsigned short h) {
    return __uint_as_float(((unsigned)h) << 16);
}

// ---------------------------------------------------------------------------
// Kernel A: pack embeddings to bf16 hi|lo rows ([code][hi x64 | lo x64]),
// fp32 norms, zero counts. 4096 threads: 4 threads per code.
// ---------------------------------------------------------------------------
__global__ void pack_e_kernel(const float* __restrict__ emb,
                              unsigned int* __restrict__ ep,   // uint view
                              float* __restrict__ enorm,
                              int* __restrict__ counts) {
    int gid = blockIdx.x * 256 + threadIdx.x;      // 0..4095
    int code = gid >> 2, tq = gid & 3;
    const float* row = emb + (size_t)code * D + tq * 16;
    unsigned int hi[8], lo[8];
    float nrm = 0.f;
#pragma unroll
    for (int i = 0; i < 4; ++i) {
        float4 v = *reinterpret_cast<const float4*>(row + i * 4);
        nrm += v.x * v.x + v.y * v.y + v.z * v.z + v.w * v.w;
        float f[4] = {v.x, v.y, v.z, v.w};
        unsigned short hh[4], ll[4];
#pragma unroll
        for (int j = 0; j < 4; ++j) {
            hh[j] = bf16_rne(f[j]);
            ll[j] = bf16_rne(f[j] - bf16_f32(hh[j]));
        }
        hi[i * 2 + 0] = (unsigned)hh[0] | ((unsigned)hh[1] << 16);
        hi[i * 2 + 1] = (unsigned)hh[2] | ((unsigned)hh[3] << 16);
        lo[i * 2 + 0] = (unsigned)ll[0] | ((unsigned)ll[1] << 16);
        lo[i * 2 + 1] = (unsigned)ll[2] | ((unsigned)ll[3] << 16);
    }
    unsigned int* orow = ep + (size_t)code * 64;   // 64 uints per code row
    *reinterpret_cast<uint4*>(orow + tq * 8)          = make_uint4(hi[0], hi[1], hi[2], hi[3]);
    *reinterpret_cast<uint4*>(orow + tq * 8 + 4)      = make_uint4(hi[4], hi[5], hi[6], hi[7]);
    *reinterpret_cast<uint4*>(orow + 32 + tq * 8)     = make_uint4(lo[0], lo[1], lo[2], lo[3]);
    *reinterpret_cast<uint4*>(orow + 32 + tq * 8 + 4) = make_uint4(lo[4], lo[5], lo[6], lo[7]);
    // row-norm: sum over the 4 threads of this code (adjacent lanes)
    nrm += __shfl_xor(nrm, 1, 64);
    nrm += __shfl_xor(nrm, 2, 64);
    if (tq == 0) enorm[code] = nrm;
    if (gid < K) counts[gid] = 0;
}

// ---------------------------------------------------------------------------
// Kernel B: MFMA VQ, LDS-staged B. Block = 256 thr = 4 waves; wave w owns
// vectors [vb + w*32, +32) (A-frags in 32 VGPRs, bf16 hi/lo) and scans ALL
// 1024 codes -> argmin is wave-local. B tiles (64 codes, packed hi|lo rows,
// 16 KB) double-buffered in LDS; staged via reg loads + XOR-swizzled
// ds_write_b128 (granule g ^ (code&7)) so frag ds_read_b128 is 2-way (free).
// dot = xh.eh + xh.el + xl.eh; dist = ||e||^2 - 2 dot (||x||^2 dropped).
// C-layout: col(code)=lane&15, row(vec)=(lane>>4)*4+reg (m89-verified).
// ---------------------------------------------------------------------------
__global__ void __launch_bounds__(256, 2)
vq_kernel(const float* __restrict__ x,
          const float* __restrict__ emb,
          const unsigned short* __restrict__ ep,
          const float* __restrict__ enormp,
          int* __restrict__ counts,
          float* __restrict__ out) {
    __shared__ __align__(16) unsigned short bt[2][64 * 128];   // 2 x 16 KB B tiles
    __shared__ __align__(16) float en[K];                      // 4 KB all code norms
    __shared__ int bks[128];

    const int t    = threadIdx.x;
    const int w    = t >> 6;
    const int lane = t & 63;
    const int q    = lane >> 4;
    const int c    = lane & 15;
    const int vb   = blockIdx.x * 128;

    // ---- all 1024 enorms -> LDS ----
    reinterpret_cast<float4*>(en)[t] = reinterpret_cast<const float4*>(enormp)[t];

    // ---- A-frags: 32 vectors/wave, bf16 hi/lo, kept in VGPRs ----
    s16x8 Ah[2][2], Al[2][2];
#pragma unroll
    for (int mt = 0; mt < 2; ++mt)
#pragma unroll
        for (int h = 0; h < 2; ++h) {
            const float* xr = x + (size_t)(vb + w * 32 + mt * 16 + c) * D + h * 32 + q * 8;
            float4 u0 = *reinterpret_cast<const float4*>(xr);
            float4 u1 = *reinterpret_cast<const float4*>(xr + 4);
            float f[8] = {u0.x, u0.y, u0.z, u0.w, u1.x, u1.y, u1.z, u1.w};
            s16x8 hiv, lov;
#pragma unroll
            for (int j = 0; j < 8; ++j) {
                unsigned short hb = bf16_rne(f[j]);
                hiv[j] = (short)hb;
                lov[j] = (short)bf16_rne(f[j] - bf16_f32(hb));
            }
            Ah[mt][h] = hiv;
            Al[mt][h] = lov;
        }

    float best[8];
    int   bk_[8];
#pragma unroll
    for (int s = 0; s < 8; ++s) { best[s] = 3.4e38f; bk_[s] = 0; }

    // staging: thread t handles flat granules f = i*256 + t (i=0..3) of tile
    uint4 stg[4];
    {
        const uint4* gp = reinterpret_cast<const uint4*>(ep);  // granule = 16 B
#pragma unroll
        for (int i = 0; i < 4; ++i) stg[i] = gp[i * 256 + t];
    }

    for (int ct = 0; ct < 16; ++ct) {
        // swizzled ds_write of prefetched tile
        unsigned short* buf = bt[ct & 1];
#pragma unroll
        for (int i = 0; i < 4; ++i) {
            int f = i * 256 + t;
            int code = f >> 4, g = f & 15;
            *reinterpret_cast<uint4*>(buf + code * 128 + (g ^ (code & 7)) * 8) = stg[i];
        }
        __syncthreads();
        if (ct < 15) {
            const uint4* gp = reinterpret_cast<const uint4*>(ep) + (size_t)(ct + 1) * 1024;
#pragma unroll
            for (int i = 0; i < 4; ++i) stg[i] = gp[i * 256 + t];
        }

#pragma unroll
        for (int g = 0; g < 4; ++g) {
            const int code_l = g * 16 + c;
            const unsigned short* bp = buf + code_l * 128;
            const int sw = (c & 7);
            s16x8 Bh0 = *reinterpret_cast<const s16x8*>(bp + ((0 + q) ^ sw) * 8);
            s16x8 Bh1 = *reinterpret_cast<const s16x8*>(bp + ((4 + q) ^ sw) * 8);
            s16x8 Bl0 = *reinterpret_cast<const s16x8*>(bp + ((8 + q) ^ sw) * 8);
            s16x8 Bl1 = *reinterpret_cast<const s16x8*>(bp + ((12 + q) ^ sw) * 8);

            const int codeG = ct * 64 + g * 16 + c;
            const float enc = en[codeG];
#pragma unroll
            for (int mt = 0; mt < 2; ++mt) {
                f32x4 acc = (f32x4){0.f, 0.f, 0.f, 0.f};
                acc = MFMA(Ah[mt][0], Bh0, acc);
                acc = MFMA(Ah[mt][1], Bh1, acc);
                acc = MFMA(Ah[mt][0], Bl0, acc);
                acc = MFMA(Ah[mt][1], Bl1, acc);
                acc = MFMA(Al[mt][0], Bh0, acc);
                acc = MFMA(Al[mt][1], Bh1, acc);
#pragma unroll
                for (int r = 0; r < 4; ++r) {
                    float dist = fmaf(-2.f, acc[r], enc);
                    int s = mt * 4 + r;
                    if (dist < best[s]) { best[s] = dist; bk_[s] = codeG; }
                }
            }
        }
        __syncthreads();   // all waves done reading buf before it's rewritten
    }

    // ---- reduce over the 16 code-columns (lexicographic: dist, index) ----
#pragma unroll
    for (int m = 1; m <= 8; m <<= 1)
#pragma unroll
        for (int s = 0; s < 8; ++s) {
            float ob = __shfl_xor(best[s], m, 64);
            int   ok = __shfl_xor(bk_[s], m, 64);
            if (ob < best[s] || (ob == best[s] && ok < bk_[s])) {
                best[s] = ob; bk_[s] = ok;
            }
        }
    if (c == 0) {
#pragma unroll
        for (int mt = 0; mt < 2; ++mt)
#pragma unroll
            for (int r = 0; r < 4; ++r) {
                int lv = w * 32 + mt * 16 + q * 4 + r;
                int kk = bk_[mt * 4 + r];
                bks[lv] = kk;
                atomicAdd(&counts[kk], 1);
            }
    }
    __syncthreads();

    // ---- gather winning rows -> out (exact fp32) ----
#pragma unroll
    for (int i = 0; i < 2; ++i) {
        int vec = i * 64 + (t >> 2), part = t & 3;
        int kk = bks[vec];
        const float4* src = reinterpret_cast<const float4*>(emb + (size_t)kk * D) + part * 4;
        float4* dst = reinterpret_cast<float4*>(out + (size_t)(vb + vec) * D) + part * 4;
#pragma unroll
        for (int j = 0; j < 4; ++j) dst[j] = src[j];
    }
}

// ---------------------------------------------------------------------------
// Kernel C: perplexity = exp(-sum p log(p+eps)), p = counts/N. 256 threads.
// ---------------------------------------------------------------------------
__global__ void perplexity_kernel(const int* __restrict__ counts,
                                  float* __restrict__ outp) {
    int t = threadIdx.x;
    float s = 0.f;
#pragma unroll
    for (int i = 0; i < 4; ++i) {
        float p = (float)counts[t + i * 256] * (1.0f / (float)N_VEC);
        s += p * logf(p + VQ_EPS);
    }
#pragma unroll
    for (int m = 1; m < 64; m <<= 1) s += __shfl_xor(s, m, 64);
    __shared__ float ws[4];
    if ((t & 63) == 0) ws[t >> 6] = s;
    __syncthreads();
    if (t == 0) *outp = expf(-(ws[0] + ws[1] + ws[2] + ws[3]));
}

// ---------------------------------------------------------------------------
extern "C" void kernel_launch(void* const* d_in, const int* in_sizes, int n_in,
                              void* d_out, int out_size, void* d_ws, size_t ws_size,
                              hipStream_t stream) {
    const float* x   = (const float*)d_in[0];   // [65536, 64] fp32
    const float* emb = (const float*)d_in[1];   // [1024, 64] fp32
    float* out = (float*)d_out;                 // 4194304 quantized + 1 perplexity

    unsigned int* ep = (unsigned int*)d_ws;                            // 256 KB packed
    float* enorm  = (float*)((char*)d_ws + (size_t)K * 128 * 2);       // 4 KB
    int*   counts = (int*)((char*)enorm + K * sizeof(float));          // 4 KB

    pack_e_kernel<<<16, 256, 0, stream>>>(emb, ep, enorm, counts);
    vq_kernel<<<N_VEC / 128, 256, 0, stream>>>(x, emb, (const unsigned short*)ep,
                                               enorm, counts, out);
    perplexity_kernel<<<1, 256, 0, stream>>>(counts, out + (size_t)N_VEC * D);
}

// Round 8
// 153.395 us; speedup vs baseline: 1.4915x; 1.0567x over previous
//
#include <hip/hip_runtime.h>
#include <math.h>

#define N_VEC 65536
#define D 64
#define K 1024
#define VQ_EPS 1e-10f

typedef __attribute__((ext_vector_type(8))) short s16x8;   // 8 bf16 = 4 VGPR
typedef __attribute__((ext_vector_type(4))) float f32x4;   // MFMA acc

#define MFMA(a, b, c) __builtin_amdgcn_mfma_f32_16x16x32_bf16((a), (b), (c), 0, 0, 0)

__device__ __forceinline__ unsigned short bf16_rne(float f) {
    unsigned u = __float_as_uint(f);
    u += 0x7fff + ((u >> 16) & 1);
    return (unsigned short)(u >> 16);
}
__device__ __forceinline__ float bf16_f32(unsigned short h) {
    return __uint_as_float(((unsigned)h) << 16);
}

// ---------------------------------------------------------------------------
// Kernel A: pack embeddings into MFMA-fragment order.
// Chunk id = ct*16 + g*4 + bg  (ct=code>>6, g=(code>>4)&3; bg: 0=hi k0-31,
// 1=hi k32-63, 2=lo k0-31, 3=lo k32-63). Within a chunk: slot q*16+c is
// 16 B = 8 bf16 of code g*16+c, k = (bg&1)*32 + q*8 .. +7.
// Fragment reads/writes in the VQ kernel are then base + lane*16 (canonical,
// conflict-free). Also fp32 norms + zero counts. 4096 thr, 4 per code.
// ---------------------------------------------------------------------------
__global__ void pack_e_kernel(const float* __restrict__ emb,
                              uint4* __restrict__ ep4,
                              float* __restrict__ enorm,
                              int* __restrict__ counts) {
    int gid = blockIdx.x * 256 + threadIdx.x;      // 0..4095
    int code = gid >> 2, tq = gid & 3;             // tq: k-quarter (16 elems)
    const float* row = emb + (size_t)code * D + tq * 16;
    unsigned int hi[8], lo[8];
    float nrm = 0.f;
#pragma unroll
    for (int i = 0; i < 4; ++i) {
        float4 v = *reinterpret_cast<const float4*>(row + i * 4);
        nrm += v.x * v.x + v.y * v.y + v.z * v.z + v.w * v.w;
        float f[4] = {v.x, v.y, v.z, v.w};
        unsigned short hh[4], ll[4];
#pragma unroll
        for (int j = 0; j < 4; ++j) {
            hh[j] = bf16_rne(f[j]);
            ll[j] = bf16_rne(f[j] - bf16_f32(hh[j]));
        }
        hi[i * 2 + 0] = (unsigned)hh[0] | ((unsigned)hh[1] << 16);
        hi[i * 2 + 1] = (unsigned)hh[2] | ((unsigned)hh[3] << 16);
        lo[i * 2 + 0] = (unsigned)ll[0] | ((unsigned)ll[1] << 16);
        lo[i * 2 + 1] = (unsigned)ll[2] | ((unsigned)ll[3] << 16);
    }
    const int ct = code >> 6, g = (code >> 4) & 3, c = code & 15;
    // this thread covers k-granules 2tq, 2tq+1 (hi and lo)
#pragma unroll
    for (int h = 0; h < 2; ++h) {
        int gran = 2 * tq + h;               // 0..7
        int bg = gran >> 2, q = gran & 3;
        ep4[(size_t)(ct * 16 + g * 4 + bg) * 64 + q * 16 + c] =
            make_uint4(hi[h * 4], hi[h * 4 + 1], hi[h * 4 + 2], hi[h * 4 + 3]);
        int granl = 8 + gran;                // lo: bg 2..3
        bg = granl >> 2; q = granl & 3;
        ep4[(size_t)(ct * 16 + g * 4 + bg) * 64 + q * 16 + c] =
            make_uint4(lo[h * 4], lo[h * 4 + 1], lo[h * 4 + 2], lo[h * 4 + 3]);
    }
    nrm += __shfl_xor(nrm, 1, 64);
    nrm += __shfl_xor(nrm, 2, 64);
    if (tq == 0) enorm[code] = nrm;
    if (gid < K) counts[gid] = 0;
}

// ---------------------------------------------------------------------------
// Kernel B: MFMA VQ. Block = 4 waves; wave w owns 32 vectors (A-frags in
// VGPRs, bf16 hi/lo) and scans all 1024 codes -> wave-local argmin.
// B tiles (16 chunks x 1024 B), double-buffered in LDS; staged via register
// uint4 loads + ds_write at flat-granule*16 (lane-contiguous = canonical
// conflict-free b128). Fragment reads: chunk*1024 + lane*16 (canonical).
// dot = xh.eh + xh.el + xl.eh; dist = ||e||^2 - 2 dot (||x||^2 dropped).
// C-layout: col(code)=lane&15, row(vec)=(lane>>4)*4+reg (m89-verified).
// ---------------------------------------------------------------------------
__global__ void __launch_bounds__(256, 2)
vq_kernel(const float* __restrict__ x,
          const float* __restrict__ emb,
          const uint4* __restrict__ ep4,
          const float* __restrict__ enormp,
          int* __restrict__ counts,
          float* __restrict__ out) {
    __shared__ __align__(16) unsigned short bt[2][64 * 128];   // 2 x 16 KB
    __shared__ __align__(16) float en[K];                      // 4 KB
    __shared__ int bks[128];

    const int t    = threadIdx.x;
    const int w    = t >> 6;
    const int lane = t & 63;
    const int q    = lane >> 4;
    const int c    = lane & 15;
    const int vb   = blockIdx.x * 128;

    // ---- all 1024 enorms -> LDS ----
    reinterpret_cast<float4*>(en)[t] = reinterpret_cast<const float4*>(enormp)[t];

    // ---- A-frags: 32 vectors/wave, bf16 hi/lo, named scalars ----
    s16x8 Ah00, Ah01, Ah10, Ah11, Al00, Al01, Al10, Al11;
#define LOAD_A(mt, h, AH, AL)                                                  \
    {                                                                          \
        const float* xr = x + (size_t)(vb + w * 32 + (mt) * 16 + c) * D        \
                            + (h) * 32 + q * 8;                                \
        float4 u0 = *reinterpret_cast<const float4*>(xr);                      \
        float4 u1 = *reinterpret_cast<const float4*>(xr + 4);                  \
        float f[8] = {u0.x, u0.y, u0.z, u0.w, u1.x, u1.y, u1.z, u1.w};         \
        s16x8 hiv, lov;                                                        \
        _Pragma("unroll") for (int j = 0; j < 8; ++j) {                        \
            unsigned short hb = bf16_rne(f[j]);                                \
            hiv[j] = (short)hb;                                                \
            lov[j] = (short)bf16_rne(f[j] - bf16_f32(hb));                     \
        }                                                                      \
        AH = hiv; AL = lov;                                                    \
    }
    LOAD_A(0, 0, Ah00, Al00)
    LOAD_A(0, 1, Ah01, Al01)
    LOAD_A(1, 0, Ah10, Al10)
    LOAD_A(1, 1, Ah11, Al11)
#undef LOAD_A

    float best[8];
    int   bk_[8];
#pragma unroll
    for (int s = 0; s < 8; ++s) { best[s] = 3.4e38f; bk_[s] = 0; }

    // ---- staging regs: thread t holds flat granules f = i*256 + t ----
    uint4 stg[4];
#pragma unroll
    for (int i = 0; i < 4; ++i) stg[i] = ep4[i * 256 + t];

    for (int ct = 0; ct < 16; ++ct) {
        // canonical ds_write: flat granule f -> buf + f*16 (lane-contiguous)
        uint4* bufW = reinterpret_cast<uint4*>(bt[ct & 1]);
#pragma unroll
        for (int i = 0; i < 4; ++i) bufW[i * 256 + t] = stg[i];
        __syncthreads();

        if (ct < 15) {   // prefetch next tile into registers
            const uint4* gp = ep4 + (size_t)(ct + 1) * 1024;
#pragma unroll
            for (int i = 0; i < 4; ++i) stg[i] = gp[i * 256 + t];
        }

        const unsigned short* bufS = bt[ct & 1];
#pragma unroll
        for (int g = 0; g < 4; ++g) {
            // canonical conflict-free b128 reads: chunk*512 shorts + lane*8
            s16x8 Bh0 = *reinterpret_cast<const s16x8*>(bufS + (g * 4 + 0) * 512 + lane * 8);
            s16x8 Bh1 = *reinterpret_cast<const s16x8*>(bufS + (g * 4 + 1) * 512 + lane * 8);
            s16x8 Bl0 = *reinterpret_cast<const s16x8*>(bufS + (g * 4 + 2) * 512 + lane * 8);
            s16x8 Bl1 = *reinterpret_cast<const s16x8*>(bufS + (g * 4 + 3) * 512 + lane * 8);

            const int codeG = ct * 64 + g * 16 + c;
            const float enc = en[codeG];

            f32x4 acc0 = (f32x4){0.f, 0.f, 0.f, 0.f};
            f32x4 acc1 = (f32x4){0.f, 0.f, 0.f, 0.f};
            acc0 = MFMA(Ah00, Bh0, acc0);  acc1 = MFMA(Ah10, Bh0, acc1);
            acc0 = MFMA(Ah01, Bh1, acc0);  acc1 = MFMA(Ah11, Bh1, acc1);
            acc0 = MFMA(Ah00, Bl0, acc0);  acc1 = MFMA(Ah10, Bl0, acc1);
            acc0 = MFMA(Ah01, Bl1, acc0);  acc1 = MFMA(Ah11, Bl1, acc1);
            acc0 = MFMA(Al00, Bh0, acc0);  acc1 = MFMA(Al10, Bh0, acc1);
            acc0 = MFMA(Al01, Bh1, acc0);  acc1 = MFMA(Al11, Bh1, acc1);

#pragma unroll
            for (int r = 0; r < 4; ++r) {
                float d0 = fmaf(-2.f, acc0[r], enc);
                if (d0 < best[r]) { best[r] = d0; bk_[r] = codeG; }
                float d1 = fmaf(-2.f, acc1[r], enc);
                if (d1 < best[4 + r]) { best[4 + r] = d1; bk_[4 + r] = codeG; }
            }
        }
        __syncthreads();   // all waves done reading buf before next rewrite
    }

    // ---- reduce over the 16 code-columns (lexicographic: dist, index) ----
#pragma unroll
    for (int m = 1; m <= 8; m <<= 1)
#pragma unroll
        for (int s = 0; s < 8; ++s) {
            float ob = __shfl_xor(best[s], m, 64);
            int   ok = __shfl_xor(bk_[s], m, 64);
            if (ob < best[s] || (ob == best[s] && ok < bk_[s])) {
                best[s] = ob; bk_[s] = ok;
            }
        }
    if (c == 0) {
#pragma unroll
        for (int s = 0; s < 8; ++s) {
            int mt = s >> 2, r = s & 3;
            int lv = w * 32 + mt * 16 + q * 4 + r;
            int kk = bk_[s];
            bks[lv] = kk;
            atomicAdd(&counts[kk], 1);
        }
    }
    __syncthreads();

    // ---- gather winning rows -> out (exact fp32) ----
#pragma unroll
    for (int i = 0; i < 2; ++i) {
        int vec = i * 64 + (t >> 2), part = t & 3;
        int kk = bks[vec];
        const float4* src = reinterpret_cast<const float4*>(emb + (size_t)kk * D) + part * 4;
        float4* dst = reinterpret_cast<float4*>(out + (size_t)(vb + vec) * D) + part * 4;
#pragma unroll
        for (int j = 0; j < 4; ++j) dst[j] = src[j];
    }
}

// ---------------------------------------------------------------------------
// Kernel C: perplexity = exp(-sum p log(p+eps)), p = counts/N. 256 threads.
// ---------------------------------------------------------------------------
__global__ void perplexity_kernel(const int* __restrict__ counts,
                                  float* __restrict__ outp) {
    int t = threadIdx.x;
    float s = 0.f;
#pragma unroll
    for (int i = 0; i < 4; ++i) {
        float p = (float)counts[t + i * 256] * (1.0f / (float)N_VEC);
        s += p * logf(p + VQ_EPS);
    }
#pragma unroll
    for (int m = 1; m < 64; m <<= 1) s += __shfl_xor(s, m, 64);
    __shared__ float ws[4];
    if ((t & 63) == 0) ws[t >> 6] = s;
    __syncthreads();
    if (t == 0) *outp = expf(-(ws[0] + ws[1] + ws[2] + ws[3]));
}

// ---------------------------------------------------------------------------
extern "C" void kernel_launch(void* const* d_in, const int* in_sizes, int n_in,
                              void* d_out, int out_size, void* d_ws, size_t ws_size,
                              hipStream_t stream) {
    const float* x   = (const float*)d_in[0];   // [65536, 64] fp32
    const float* emb = (const float*)d_in[1];   // [1024, 64] fp32
    float* out = (float*)d_out;                 // 4194304 quantized + 1 perplexity

    uint4* ep     = (uint4*)d_ws;                                      // 256 KB packed
    float* enorm  = (float*)((char*)d_ws + (size_t)K * 128 * 2);       // 4 KB
    int*   counts = (int*)((char*)enorm + K * sizeof(float));          // 4 KB

    pack_e_kernel<<<16, 256, 0, stream>>>(emb, ep, enorm, counts);
    vq_kernel<<<N_VEC / 128, 256, 0, stream>>>(x, emb, ep, enorm, counts, out);
    perplexity_kernel<<<1, 256, 0, stream>>>(counts, out + (size_t)N_VEC * D);
}

// Round 9
// 142.007 us; speedup vs baseline: 1.6111x; 1.0802x over previous
//
#include <hip/hip_runtime.h>
#include <math.h>

#define N_VEC 65536
#define D 64
#define K 1024
#define VQ_EPS 1e-10f

typedef __attribute__((ext_vector_type(8))) short s16x8;   // 8 bf16 = 4 VGPR
typedef __attribute__((ext_vector_type(4))) float f32x4;   // MFMA acc

#define MFMA(a, b, c) __builtin_amdgcn_mfma_f32_16x16x32_bf16((a), (b), (c), 0, 0, 0)

__device__ __forceinline__ unsigned short bf16_rne(float f) {
    unsigned u = __float_as_uint(f);
    u += 0x7fff + ((u >> 16) & 1);
    return (unsigned short)(u >> 16);
}
__device__ __forceinline__ float bf16_f32(unsigned short h) {
    return __uint_as_float(((unsigned)h) << 16);
}

// async global->LDS DMA, 16 B per lane; LDS dest = wave-uniform base + lane*16
__device__ __forceinline__ void async_load16(const void* g, void* lds_generic) {
    __builtin_amdgcn_global_load_lds(
        (const __attribute__((address_space(1))) unsigned int*)g,
        (__attribute__((address_space(3))) unsigned int*)lds_generic, 16, 0, 0);
}

// ---------------------------------------------------------------------------
// Kernel A (UNCHANGED from R8 — benched correct): pack embeddings into
// MFMA-fragment order. Chunk id = ct*16 + g*4 + bg (bg: 0=hi k0-31, 1=hi
// k32-63, 2=lo k0-31, 3=lo k32-63). Slot q*16+c in a chunk = 16 B = 8 bf16
// of code g*16+c, k=(bg&1)*32+q*8.. Also fp32 norms + zero counts.
// ---------------------------------------------------------------------------
__global__ void pack_e_kernel(const float* __restrict__ emb,
                              uint4* __restrict__ ep4,
                              float* __restrict__ enorm,
                              int* __restrict__ counts) {
    int gid = blockIdx.x * 256 + threadIdx.x;      // 0..4095
    int code = gid >> 2, tq = gid & 3;             // tq: k-quarter (16 elems)
    const float* row = emb + (size_t)code * D + tq * 16;
    unsigned int hi[8], lo[8];
    float nrm = 0.f;
#pragma unroll
    for (int i = 0; i < 4; ++i) {
        float4 v = *reinterpret_cast<const float4*>(row + i * 4);
        nrm += v.x * v.x + v.y * v.y + v.z * v.z + v.w * v.w;
        float f[4] = {v.x, v.y, v.z, v.w};
        unsigned short hh[4], ll[4];
#pragma unroll
        for (int j = 0; j < 4; ++j) {
            hh[j] = bf16_rne(f[j]);
            ll[j] = bf16_rne(f[j] - bf16_f32(hh[j]));
        }
        hi[i * 2 + 0] = (unsigned)hh[0] | ((unsigned)hh[1] << 16);
        hi[i * 2 + 1] = (unsigned)hh[2] | ((unsigned)hh[3] << 16);
        lo[i * 2 + 0] = (unsigned)ll[0] | ((unsigned)ll[1] << 16);
        lo[i * 2 + 1] = (unsigned)ll[2] | ((unsigned)ll[3] << 16);
    }
    const int ct = code >> 6, g = (code >> 4) & 3, c = code & 15;
#pragma unroll
    for (int h = 0; h < 2; ++h) {
        int gran = 2 * tq + h;               // 0..7
        int bg = gran >> 2, q = gran & 3;
        ep4[(size_t)(ct * 16 + g * 4 + bg) * 64 + q * 16 + c] =
            make_uint4(hi[h * 4], hi[h * 4 + 1], hi[h * 4 + 2], hi[h * 4 + 3]);
        int granl = 8 + gran;                // lo: bg 2..3
        bg = granl >> 2; q = granl & 3;
        ep4[(size_t)(ct * 16 + g * 4 + bg) * 64 + q * 16 + c] =
            make_uint4(lo[h * 4], lo[h * 4 + 1], lo[h * 4 + 2], lo[h * 4 + 3]);
    }
    nrm += __shfl_xor(nrm, 1, 64);
    nrm += __shfl_xor(nrm, 2, 64);
    if (tq == 0) enorm[code] = nrm;
    if (gid < K) counts[gid] = 0;
}

// ---------------------------------------------------------------------------
// Kernel B: MFMA VQ with ZERO large loop-carried register state (the R3/R6/R8
// spill killer). A-tiles AND B-tiles live in LDS, fragment-ordered so every
// access is the canonical conflict-free base + lane*16 b128 pattern.
//  - A: 32 KB, written once per block (wave-private region, fragment order);
//    re-read per ct via volatile ds_read_b128 (volatile blocks LICM from
//    hoisting the 32 VGPRs back into loop-carried state).
//  - B: 2 x 16 KB double buffer, staged by global_load_lds DMA (no staging
//    VGPRs, no ds_writes); barrier vmcnt(0) drains it (m97 pattern).
//  - loop-carried: best[8]/bk_[8] + pointers only.
// dot = xh.eh + xh.el + xl.eh; dist = ||e||^2 - 2 dot (||x||^2 dropped).
// C-layout: col(code)=lane&15, row(vec)=(lane>>4)*4+reg (m89-verified).
// ---------------------------------------------------------------------------
__global__ void __launch_bounds__(256, 2)
vq_kernel(const float* __restrict__ x,
          const float* __restrict__ emb,
          const uint4* __restrict__ ep4,
          const float* __restrict__ enormp,
          int* __restrict__ counts,
          float* __restrict__ out) {
    __shared__ __align__(16) unsigned short bt[2][64 * 128];   // 2 x 16 KB B
    __shared__ __align__(16) unsigned short at[4][8][512];     // 32 KB A
    __shared__ int bks[128];

    const int t    = threadIdx.x;
    const int w    = t >> 6;
    const int lane = t & 63;
    const int q    = lane >> 4;
    const int c    = lane & 15;
    const int vb   = blockIdx.x * 128;

    // ---- stage A: convert 32 vecs/wave to bf16 hi/lo frags, write to LDS
    //      (wave-private region; regs die immediately after the write) ----
#define STAGE_A(mt, h)                                                         \
    {                                                                          \
        const float* xr = x + (size_t)(vb + w * 32 + (mt) * 16 + c) * D        \
                            + (h) * 32 + q * 8;                                \
        float4 u0 = *reinterpret_cast<const float4*>(xr);                      \
        float4 u1 = *reinterpret_cast<const float4*>(xr + 4);                  \
        float f[8] = {u0.x, u0.y, u0.z, u0.w, u1.x, u1.y, u1.z, u1.w};         \
        s16x8 hiv, lov;                                                        \
        _Pragma("unroll") for (int j = 0; j < 8; ++j) {                        \
            unsigned short hb = bf16_rne(f[j]);                                \
            hiv[j] = (short)hb;                                                \
            lov[j] = (short)bf16_rne(f[j] - bf16_f32(hb));                     \
        }                                                                      \
        reinterpret_cast<s16x8*>(&at[w][((mt) * 2 + (h)) * 2 + 0][0])[lane] = hiv; \
        reinterpret_cast<s16x8*>(&at[w][((mt) * 2 + (h)) * 2 + 1][0])[lane] = lov; \
    }
    STAGE_A(0, 0)
    STAGE_A(0, 1)
    STAGE_A(1, 0)
    STAGE_A(1, 1)
#undef STAGE_A

    // ---- prologue: DMA tile 0's chunks (wave w -> chunks w*4..w*4+3) ----
    {
        const char* gbase = (const char*)ep4 + (size_t)(w * 4) * 1024 + lane * 16;
        char* lbase = (char*)bt[0] + (w * 4) * 1024;
#pragma unroll
        for (int i = 0; i < 4; ++i)
            async_load16(gbase + i * 1024, lbase + i * 1024);
    }

    float best[8];
    int   bk_[8];
#pragma unroll
    for (int s = 0; s < 8; ++s) { best[s] = 3.4e38f; bk_[s] = 0; }

    for (int ct = 0; ct < 16; ++ct) {
        __syncthreads();   // vmcnt(0)+barrier: tile ct ready in bt[ct&1];
                           // everyone done reading bt[(ct+1)&1]

        if (ct < 15) {     // DMA next tile into the other buffer
            const char* gbase = (const char*)ep4
                + (size_t)((ct + 1) * 16 + w * 4) * 1024 + lane * 16;
            char* lbase = (char*)bt[(ct + 1) & 1] + (w * 4) * 1024;
#pragma unroll
            for (int i = 0; i < 4; ++i)
                async_load16(gbase + i * 1024, lbase + i * 1024);
        }

        // A-frags: volatile canonical b128 reads (live only this iteration)
        const volatile s16x8* ap = reinterpret_cast<const volatile s16x8*>(&at[w][0][0]);
        s16x8 Ah00 = ap[0 * 64 + lane];
        s16x8 Al00 = ap[1 * 64 + lane];
        s16x8 Ah01 = ap[2 * 64 + lane];
        s16x8 Al01 = ap[3 * 64 + lane];
        s16x8 Ah10 = ap[4 * 64 + lane];
        s16x8 Al10 = ap[5 * 64 + lane];
        s16x8 Ah11 = ap[6 * 64 + lane];
        s16x8 Al11 = ap[7 * 64 + lane];

        const unsigned short* bufS = bt[ct & 1];
#pragma unroll
        for (int g = 0; g < 4; ++g) {
            s16x8 Bh0 = *reinterpret_cast<const s16x8*>(bufS + (g * 4 + 0) * 512 + lane * 8);
            s16x8 Bh1 = *reinterpret_cast<const s16x8*>(bufS + (g * 4 + 1) * 512 + lane * 8);
            s16x8 Bl0 = *reinterpret_cast<const s16x8*>(bufS + (g * 4 + 2) * 512 + lane * 8);
            s16x8 Bl1 = *reinterpret_cast<const s16x8*>(bufS + (g * 4 + 3) * 512 + lane * 8);

            const int codeG = ct * 64 + g * 16 + c;
            const float enc = enormp[codeG];       // L2-resident, VMEM pipe idle

            f32x4 acc0 = (f32x4){0.f, 0.f, 0.f, 0.f};
            f32x4 acc1 = (f32x4){0.f, 0.f, 0.f, 0.f};
            acc0 = MFMA(Ah00, Bh0, acc0);  acc1 = MFMA(Ah10, Bh0, acc1);
            acc0 = MFMA(Ah01, Bh1, acc0);  acc1 = MFMA(Ah11, Bh1, acc1);
            acc0 = MFMA(Ah00, Bl0, acc0);  acc1 = MFMA(Ah10, Bl0, acc1);
            acc0 = MFMA(Ah01, Bl1, acc0);  acc1 = MFMA(Ah11, Bl1, acc1);
            acc0 = MFMA(Al00, Bh0, acc0);  acc1 = MFMA(Al10, Bh0, acc1);
            acc0 = MFMA(Al01, Bh1, acc0);  acc1 = MFMA(Al11, Bh1, acc1);

#pragma unroll
            for (int r = 0; r < 4; ++r) {
                float d0 = fmaf(-2.f, acc0[r], enc);
                if (d0 < best[r]) { best[r] = d0; bk_[r] = codeG; }
                float d1 = fmaf(-2.f, acc1[r], enc);
                if (d1 < best[4 + r]) { best[4 + r] = d1; bk_[4 + r] = codeG; }
            }
        }
    }

    // ---- reduce over the 16 code-columns (lexicographic: dist, index) ----
#pragma unroll
    for (int m = 1; m <= 8; m <<= 1)
#pragma unroll
        for (int s = 0; s < 8; ++s) {
            float ob = __shfl_xor(best[s], m, 64);
            int   ok = __shfl_xor(bk_[s], m, 64);
            if (ob < best[s] || (ob == best[s] && ok < bk_[s])) {
                best[s] = ob; bk_[s] = ok;
            }
        }
    if (c == 0) {
#pragma unroll
        for (int s = 0; s < 8; ++s) {
            int mt = s >> 2, r = s & 3;
            int lv = w * 32 + mt * 16 + q * 4 + r;
            int kk = bk_[s];
            bks[lv] = kk;
            atomicAdd(&counts[kk], 1);
        }
    }
    __syncthreads();

    // ---- gather winning rows -> out (exact fp32) ----
#pragma unroll
    for (int i = 0; i < 2; ++i) {
        int vec = i * 64 + (t >> 2), part = t & 3;
        int kk = bks[vec];
        const float4* src = reinterpret_cast<const float4*>(emb + (size_t)kk * D) + part * 4;
        float4* dst = reinterpret_cast<float4*>(out + (size_t)(vb + vec) * D) + part * 4;
#pragma unroll
        for (int j = 0; j < 4; ++j) dst[j] = src[j];
    }
}

// ---------------------------------------------------------------------------
// Kernel C: perplexity = exp(-sum p log(p+eps)), p = counts/N. 256 threads.
// ---------------------------------------------------------------------------
__global__ void perplexity_kernel(const int* __restrict__ counts,
                                  float* __restrict__ outp) {
    int t = threadIdx.x;
    float s = 0.f;
#pragma unroll
    for (int i = 0; i < 4; ++i) {
        float p = (float)counts[t + i * 256] * (1.0f / (float)N_VEC);
        s += p * logf(p + VQ_EPS);
    }
#pragma unroll
    for (int m = 1; m < 64; m <<= 1) s += __shfl_xor(s, m, 64);
    __shared__ float ws[4];
    if ((t & 63) == 0) ws[t >> 6] = s;
    __syncthreads();
    if (t == 0) *outp = expf(-(ws[0] + ws[1] + ws[2] + ws[3]));
}

// ---------------------------------------------------------------------------
extern "C" void kernel_launch(void* const* d_in, const int* in_sizes, int n_in,
                              void* d_out, int out_size, void* d_ws, size_t ws_size,
                              hipStream_t stream) {
    const float* x   = (const float*)d_in[0];   // [65536, 64] fp32
    const float* emb = (const float*)d_in[1];   // [1024, 64] fp32
    float* out = (float*)d_out;                 // 4194304 quantized + 1 perplexity

    uint4* ep     = (uint4*)d_ws;                                      // 256 KB packed
    float* enorm  = (float*)((char*)d_ws + (size_t)K * 128 * 2);       // 4 KB
    int*   counts = (int*)((char*)enorm + K * sizeof(float));          // 4 KB

    pack_e_kernel<<<16, 256, 0, stream>>>(emb, ep, enorm, counts);
    vq_kernel<<<N_VEC / 128, 256, 0, stream>>>(x, emb, ep, enorm, counts, out);
    perplexity_kernel<<<1, 256, 0, stream>>>(counts, out + (size_t)N_VEC * D);
}

// Round 10
// 139.794 us; speedup vs baseline: 1.6366x; 1.0158x over previous
//
#include <hip/hip_runtime.h>
#include <math.h>

#define N_VEC 65536
#define D 64
#define K 1024
#define VQ_EPS 1e-10f

typedef __attribute__((ext_vector_type(8))) short s16x8;   // 8 bf16 = 4 VGPR
typedef __attribute__((ext_vector_type(4))) float f32x4;   // MFMA acc

#define MFMA(a, b, c) __builtin_amdgcn_mfma_f32_16x16x32_bf16((a), (b), (c), 0, 0, 0)

__device__ __forceinline__ unsigned short bf16_rne(float f) {
    unsigned u = __float_as_uint(f);
    u += 0x7fff + ((u >> 16) & 1);
    return (unsigned short)(u >> 16);
}
__device__ __forceinline__ float bf16_f32(unsigned short h) {
    return __uint_as_float(((unsigned)h) << 16);
}

// async global->LDS DMA, 16 B per lane; LDS dest = wave-uniform base + lane*16
__device__ __forceinline__ void async_load16(const void* g, void* lds_generic) {
    __builtin_amdgcn_global_load_lds(
        (const __attribute__((address_space(1))) unsigned int*)g,
        (__attribute__((address_space(3))) unsigned int*)lds_generic, 16, 0, 0);
}

// ---------------------------------------------------------------------------
// Kernel A (unchanged, benched correct): pack embeddings into MFMA-fragment
// order. Chunk id = ct*16 + g*4 + bg (bg: 0=hi k0-31, 1=hi k32-63,
// 2=lo k0-31, 3=lo k32-63). Slot q*16+c in a chunk = 16 B = 8 bf16 of code
// g*16+c, k=(bg&1)*32+q*8.. Also fp32 norms + zero counts.
// ---------------------------------------------------------------------------
__global__ void pack_e_kernel(const float* __restrict__ emb,
                              uint4* __restrict__ ep4,
                              float* __restrict__ enorm,
                              int* __restrict__ counts) {
    int gid = blockIdx.x * 256 + threadIdx.x;      // 0..4095
    int code = gid >> 2, tq = gid & 3;             // tq: k-quarter (16 elems)
    const float* row = emb + (size_t)code * D + tq * 16;
    unsigned int hi[8], lo[8];
    float nrm = 0.f;
#pragma unroll
    for (int i = 0; i < 4; ++i) {
        float4 v = *reinterpret_cast<const float4*>(row + i * 4);
        nrm += v.x * v.x + v.y * v.y + v.z * v.z + v.w * v.w;
        float f[4] = {v.x, v.y, v.z, v.w};
        unsigned short hh[4], ll[4];
#pragma unroll
        for (int j = 0; j < 4; ++j) {
            hh[j] = bf16_rne(f[j]);
            ll[j] = bf16_rne(f[j] - bf16_f32(hh[j]));
        }
        hi[i * 2 + 0] = (unsigned)hh[0] | ((unsigned)hh[1] << 16);
        hi[i * 2 + 1] = (unsigned)hh[2] | ((unsigned)hh[3] << 16);
        lo[i * 2 + 0] = (unsigned)ll[0] | ((unsigned)ll[1] << 16);
        lo[i * 2 + 1] = (unsigned)ll[2] | ((unsigned)ll[3] << 16);
    }
    const int ct = code >> 6, g = (code >> 4) & 3, c = code & 15;
#pragma unroll
    for (int h = 0; h < 2; ++h) {
        int gran = 2 * tq + h;               // 0..7
        int bg = gran >> 2, q = gran & 3;
        ep4[(size_t)(ct * 16 + g * 4 + bg) * 64 + q * 16 + c] =
            make_uint4(hi[h * 4], hi[h * 4 + 1], hi[h * 4 + 2], hi[h * 4 + 3]);
        int granl = 8 + gran;                // lo: bg 2..3
        bg = granl >> 2; q = granl & 3;
        ep4[(size_t)(ct * 16 + g * 4 + bg) * 64 + q * 16 + c] =
            make_uint4(lo[h * 4], lo[h * 4 + 1], lo[h * 4 + 2], lo[h * 4 + 3]);
    }
    nrm += __shfl_xor(nrm, 1, 64);
    nrm += __shfl_xor(nrm, 2, 64);
    if (tq == 0) enorm[code] = nrm;
    if (gid < K) counts[gid] = 0;
}

// ---------------------------------------------------------------------------
// Kernel B: MFMA VQ, zero large loop-carried register state.
//  - A: 32 KB LDS, written once (fragment order), volatile b128 re-reads.
//  - B: 2 x 16 KB LDS double buffer, staged by global_load_lds DMA.
//  - en: 4 KB LDS (NOT global! a global load in the K-loop shares the FIFO
//    vmcnt with the DMA queue — waiting for it drains ALL outstanding
//    prefetches, serializing the pipeline. That was R9's 5x-off-floor stall.)
//  - loop-carried: best[8]/bk_[8] + pointers only.
// All LDS traffic is the canonical conflict-free base + lane*16 pattern.
// dot = xh.eh + xh.el + xl.eh; dist = ||e||^2 - 2 dot (||x||^2 dropped).
// C-layout: col(code)=lane&15, row(vec)=(lane>>4)*4+reg (m89-verified).
// ---------------------------------------------------------------------------
__global__ void __launch_bounds__(256, 2)
vq_kernel(const float* __restrict__ x,
          const float* __restrict__ emb,
          const uint4* __restrict__ ep4,
          const float* __restrict__ enormp,
          int* __restrict__ counts,
          float* __restrict__ out) {
    __shared__ __align__(16) unsigned short bt[2][64 * 128];   // 2 x 16 KB B
    __shared__ __align__(16) unsigned short at[4][8][512];     // 32 KB A
    __shared__ __align__(16) float en[K];                      // 4 KB norms
    __shared__ int bks[128];

    const int t    = threadIdx.x;
    const int w    = t >> 6;
    const int lane = t & 63;
    const int q    = lane >> 4;
    const int c    = lane & 15;
    const int vb   = blockIdx.x * 128;

    // ---- all 1024 enorms -> LDS (one b128 per thread) ----
    reinterpret_cast<float4*>(en)[t] = reinterpret_cast<const float4*>(enormp)[t];

    // ---- stage A: 32 vecs/wave as bf16 hi/lo frags -> LDS (wave-private) ----
#define STAGE_A(mt, h)                                                         \
    {                                                                          \
        const float* xr = x + (size_t)(vb + w * 32 + (mt) * 16 + c) * D        \
                            + (h) * 32 + q * 8;                                \
        float4 u0 = *reinterpret_cast<const float4*>(xr);                      \
        float4 u1 = *reinterpret_cast<const float4*>(xr + 4);                  \
        float f[8] = {u0.x, u0.y, u0.z, u0.w, u1.x, u1.y, u1.z, u1.w};         \
        s16x8 hiv, lov;                                                        \
        _Pragma("unroll") for (int j = 0; j < 8; ++j) {                        \
            unsigned short hb = bf16_rne(f[j]);                                \
            hiv[j] = (short)hb;                                                \
            lov[j] = (short)bf16_rne(f[j] - bf16_f32(hb));                     \
        }                                                                      \
        reinterpret_cast<s16x8*>(&at[w][((mt) * 2 + (h)) * 2 + 0][0])[lane] = hiv; \
        reinterpret_cast<s16x8*>(&at[w][((mt) * 2 + (h)) * 2 + 1][0])[lane] = lov; \
    }
    STAGE_A(0, 0)
    STAGE_A(0, 1)
    STAGE_A(1, 0)
    STAGE_A(1, 1)
#undef STAGE_A

    // ---- prologue: DMA tile 0's chunks (wave w -> chunks w*4..w*4+3) ----
    {
        const char* gbase = (const char*)ep4 + (size_t)(w * 4) * 1024 + lane * 16;
        char* lbase = (char*)bt[0] + (w * 4) * 1024;
#pragma unroll
        for (int i = 0; i < 4; ++i)
            async_load16(gbase + i * 1024, lbase + i * 1024);
    }

    float best[8];
    int   bk_[8];
#pragma unroll
    for (int s = 0; s < 8; ++s) { best[s] = 3.4e38f; bk_[s] = 0; }

    for (int ct = 0; ct < 16; ++ct) {
        __syncthreads();   // vmcnt(0)+barrier: tile ct ready in bt[ct&1];
                           // everyone done reading bt[(ct+1)&1]

        if (ct < 15) {     // DMA next tile into the other buffer
            const char* gbase = (const char*)ep4
                + (size_t)((ct + 1) * 16 + w * 4) * 1024 + lane * 16;
            char* lbase = (char*)bt[(ct + 1) & 1] + (w * 4) * 1024;
#pragma unroll
            for (int i = 0; i < 4; ++i)
                async_load16(gbase + i * 1024, lbase + i * 1024);
        }

        // A-frags: volatile canonical b128 reads (live only this iteration)
        const volatile s16x8* ap = reinterpret_cast<const volatile s16x8*>(&at[w][0][0]);
        s16x8 Ah00 = ap[0 * 64 + lane];
        s16x8 Al00 = ap[1 * 64 + lane];
        s16x8 Ah01 = ap[2 * 64 + lane];
        s16x8 Al01 = ap[3 * 64 + lane];
        s16x8 Ah10 = ap[4 * 64 + lane];
        s16x8 Al10 = ap[5 * 64 + lane];
        s16x8 Ah11 = ap[6 * 64 + lane];
        s16x8 Al11 = ap[7 * 64 + lane];

        const unsigned short* bufS = bt[ct & 1];
#pragma unroll
        for (int g = 0; g < 4; ++g) {
            s16x8 Bh0 = *reinterpret_cast<const s16x8*>(bufS + (g * 4 + 0) * 512 + lane * 8);
            s16x8 Bh1 = *reinterpret_cast<const s16x8*>(bufS + (g * 4 + 1) * 512 + lane * 8);
            s16x8 Bl0 = *reinterpret_cast<const s16x8*>(bufS + (g * 4 + 2) * 512 + lane * 8);
            s16x8 Bl1 = *reinterpret_cast<const s16x8*>(bufS + (g * 4 + 3) * 512 + lane * 8);

            const int codeG = ct * 64 + g * 16 + c;
            const float enc = en[codeG];           // LDS: lgkmcnt only, no vmcnt

            f32x4 acc0 = (f32x4){0.f, 0.f, 0.f, 0.f};
            f32x4 acc1 = (f32x4){0.f, 0.f, 0.f, 0.f};
            acc0 = MFMA(Ah00, Bh0, acc0);  acc1 = MFMA(Ah10, Bh0, acc1);
            acc0 = MFMA(Ah01, Bh1, acc0);  acc1 = MFMA(Ah11, Bh1, acc1);
            acc0 = MFMA(Ah00, Bl0, acc0);  acc1 = MFMA(Ah10, Bl0, acc1);
            acc0 = MFMA(Ah01, Bl1, acc0);  acc1 = MFMA(Ah11, Bl1, acc1);
            acc0 = MFMA(Al00, Bh0, acc0);  acc1 = MFMA(Al10, Bh0, acc1);
            acc0 = MFMA(Al01, Bh1, acc0);  acc1 = MFMA(Al11, Bh1, acc1);

#pragma unroll
            for (int r = 0; r < 4; ++r) {
                float d0 = fmaf(-2.f, acc0[r], enc);
                if (d0 < best[r]) { best[r] = d0; bk_[r] = codeG; }
                float d1 = fmaf(-2.f, acc1[r], enc);
                if (d1 < best[4 + r]) { best[4 + r] = d1; bk_[4 + r] = codeG; }
            }
        }
    }

    // ---- reduce over the 16 code-columns (lexicographic: dist, index) ----
#pragma unroll
    for (int m = 1; m <= 8; m <<= 1)
#pragma unroll
        for (int s = 0; s < 8; ++s) {
            float ob = __shfl_xor(best[s], m, 64);
            int   ok = __shfl_xor(bk_[s], m, 64);
            if (ob < best[s] || (ob == best[s] && ok < bk_[s])) {
                best[s] = ob; bk_[s] = ok;
            }
        }
    if (c == 0) {
#pragma unroll
        for (int s = 0; s < 8; ++s) {
            int mt = s >> 2, r = s & 3;
            int lv = w * 32 + mt * 16 + q * 4 + r;
            int kk = bk_[s];
            bks[lv] = kk;
            atomicAdd(&counts[kk], 1);
        }
    }
    __syncthreads();

    // ---- gather winning rows -> out (exact fp32) ----
#pragma unroll
    for (int i = 0; i < 2; ++i) {
        int vec = i * 64 + (t >> 2), part = t & 3;
        int kk = bks[vec];
        const float4* src = reinterpret_cast<const float4*>(emb + (size_t)kk * D) + part * 4;
        float4* dst = reinterpret_cast<float4*>(out + (size_t)(vb + vec) * D) + part * 4;
#pragma unroll
        for (int j = 0; j < 4; ++j) dst[j] = src[j];
    }
}

// ---------------------------------------------------------------------------
// Kernel C: perplexity = exp(-sum p log(p+eps)), p = counts/N. 256 threads.
// ---------------------------------------------------------------------------
__global__ void perplexity_kernel(const int* __restrict__ counts,
                                  float* __restrict__ outp) {
    int t = threadIdx.x;
    float s = 0.f;
#pragma unroll
    for (int i = 0; i < 4; ++i) {
        float p = (float)counts[t + i * 256] * (1.0f / (float)N_VEC);
        s += p * logf(p + VQ_EPS);
    }
#pragma unroll
    for (int m = 1; m < 64; m <<= 1) s += __shfl_xor(s, m, 64);
    __shared__ float ws[4];
    if ((t & 63) == 0) ws[t >> 6] = s;
    __syncthreads();
    if (t == 0) *outp = expf(-(ws[0] + ws[1] + ws[2] + ws[3]));
}

// ---------------------------------------------------------------------------
extern "C" void kernel_launch(void* const* d_in, const int* in_sizes, int n_in,
                              void* d_out, int out_size, void* d_ws, size_t ws_size,
                              hipStream_t stream) {
    const float* x   = (const float*)d_in[0];   // [65536, 64] fp32
    const float* emb = (const float*)d_in[1];   // [1024, 64] fp32
    float* out = (float*)d_out;                 // 4194304 quantized + 1 perplexity

    uint4* ep     = (uint4*)d_ws;                                      // 256 KB packed
    float* enorm  = (float*)((char*)d_ws + (size_t)K * 128 * 2);       // 4 KB
    int*   counts = (int*)((char*)enorm + K * sizeof(float));          // 4 KB

    pack_e_kernel<<<16, 256, 0, stream>>>(emb, ep, enorm, counts);
    vq_kernel<<<N_VEC / 128, 256, 0, stream>>>(x, emb, ep, enorm, counts, out);
    perplexity_kernel<<<1, 256, 0, stream>>>(counts, out + (size_t)N_VEC * D);
}

// Round 11
// 132.079 us; speedup vs baseline: 1.7322x; 1.0584x over previous
//
#include <hip/hip_runtime.h>
#include <math.h>

#define N_VEC 65536
#define D 64
#define K 1024
#define VQ_EPS 1e-10f

typedef __attribute__((ext_vector_type(8))) short s16x8;   // 8 bf16 = 4 VGPR
typedef __attribute__((ext_vector_type(4))) float f32x4;   // MFMA acc

#define MFMA(a, b, c) __builtin_amdgcn_mfma_f32_16x16x32_bf16((a), (b), (c), 0, 0, 0)

__device__ __forceinline__ unsigned short bf16_rne(float f) {
    unsigned u = __float_as_uint(f);
    u += 0x7fff + ((u >> 16) & 1);
    return (unsigned short)(u >> 16);
}
__device__ __forceinline__ float bf16_f32(unsigned short h) {
    return __uint_as_float(((unsigned)h) << 16);
}

// async global->LDS DMA, 16 B per lane; LDS dest = wave-uniform base + lane*16
__device__ __forceinline__ void async_load16(const void* g, void* lds_generic) {
    __builtin_amdgcn_global_load_lds(
        (const __attribute__((address_space(1))) unsigned int*)g,
        (__attribute__((address_space(3))) unsigned int*)lds_generic, 16, 0, 0);
}

// ---------------------------------------------------------------------------
// Kernel A (unchanged, benched correct): pack embeddings into MFMA-fragment
// order. Chunk id = ct*16 + g*4 + bg (bg: 0=hi k0-31, 1=hi k32-63,
// 2=lo k0-31, 3=lo k32-63). Slot q*16+c in a chunk = 16 B = 8 bf16 of code
// g*16+c, k=(bg&1)*32+q*8.. Also fp32 norms + zero counts.
// ---------------------------------------------------------------------------
__global__ void pack_e_kernel(const float* __restrict__ emb,
                              uint4* __restrict__ ep4,
                              float* __restrict__ enorm,
                              int* __restrict__ counts) {
    int gid = blockIdx.x * 256 + threadIdx.x;      // 0..4095
    int code = gid >> 2, tq = gid & 3;             // tq: k-quarter (16 elems)
    const float* row = emb + (size_t)code * D + tq * 16;
    unsigned int hi[8], lo[8];
    float nrm = 0.f;
#pragma unroll
    for (int i = 0; i < 4; ++i) {
        float4 v = *reinterpret_cast<const float4*>(row + i * 4);
        nrm += v.x * v.x + v.y * v.y + v.z * v.z + v.w * v.w;
        float f[4] = {v.x, v.y, v.z, v.w};
        unsigned short hh[4], ll[4];
#pragma unroll
        for (int j = 0; j < 4; ++j) {
            hh[j] = bf16_rne(f[j]);
            ll[j] = bf16_rne(f[j] - bf16_f32(hh[j]));
        }
        hi[i * 2 + 0] = (unsigned)hh[0] | ((unsigned)hh[1] << 16);
        hi[i * 2 + 1] = (unsigned)hh[2] | ((unsigned)hh[3] << 16);
        lo[i * 2 + 0] = (unsigned)ll[0] | ((unsigned)ll[1] << 16);
        lo[i * 2 + 1] = (unsigned)ll[2] | ((unsigned)ll[3] << 16);
    }
    const int ct = code >> 6, g = (code >> 4) & 3, c = code & 15;
#pragma unroll
    for (int h = 0; h < 2; ++h) {
        int gran = 2 * tq + h;               // 0..7
        int bg = gran >> 2, q = gran & 3;
        ep4[(size_t)(ct * 16 + g * 4 + bg) * 64 + q * 16 + c] =
            make_uint4(hi[h * 4], hi[h * 4 + 1], hi[h * 4 + 2], hi[h * 4 + 3]);
        int granl = 8 + gran;                // lo: bg 2..3
        bg = granl >> 2; q = granl & 3;
        ep4[(size_t)(ct * 16 + g * 4 + bg) * 64 + q * 16 + c] =
            make_uint4(lo[h * 4], lo[h * 4 + 1], lo[h * 4 + 2], lo[h * 4 + 3]);
    }
    nrm += __shfl_xor(nrm, 1, 64);
    nrm += __shfl_xor(nrm, 2, 64);
    if (tq == 0) enorm[code] = nrm;
    if (gid < K) counts[gid] = 0;
}

// ---------------------------------------------------------------------------
// Kernel B: MFMA VQ, occupancy-first design.
//  - Wave owns 16 vectors; A = 4 named s16x8 (16 VGPRs) — no spill risk,
//    no A-LDS, no volatile re-reads (R10's serialized-latency source).
//  - Block = 64 vectors, grid = 1024 -> with 36.4 KB LDS: 4 blocks/CU,
//    16 waves/CU (50%): 4 independent barrier-groups hide each other's
//    stalls (R6-R10 plateaued at 2 lockstep blocks/CU).
//  - B: 2 x 16 KB LDS dbuf via global_load_lds DMA (zero staging VGPRs).
//  - Epilogue folded into MFMA: acc init = -enc/2 (C operand), then
//    argMAX of score = dot - enc/2  (dist = -2*score, exact monotone map,
//    exact tie equivalence). Strict >, ascending code = first-occurrence.
// C-layout: col(code)=lane&15, row(vec)=(lane>>4)*4+reg (m89-verified).
// ---------------------------------------------------------------------------
__global__ void __launch_bounds__(256, 4)
vq_kernel(const float* __restrict__ x,
          const float* __restrict__ emb,
          const uint4* __restrict__ ep4,
          const float* __restrict__ enormp,
          int* __restrict__ counts,
          float* __restrict__ out) {
    __shared__ __align__(16) unsigned short bt[2][64 * 128];   // 2 x 16 KB B
    __shared__ __align__(16) float en[K];                      // 4 KB norms
    __shared__ int bks[64];

    const int t    = threadIdx.x;
    const int w    = t >> 6;
    const int lane = t & 63;
    const int q    = lane >> 4;
    const int c    = lane & 15;
    const int vb   = blockIdx.x * 64;

    // ---- all 1024 enorms -> LDS (one float4 per thread) ----
    reinterpret_cast<float4*>(en)[t] = reinterpret_cast<const float4*>(enormp)[t];

    // ---- A-frags: 16 vectors/wave, bf16 hi/lo, 4 named s16x8 (16 VGPRs) ----
    s16x8 Ah0, Ah1, Al0, Al1;
#define LOAD_A(h, AH, AL)                                                      \
    {                                                                          \
        const float* xr = x + (size_t)(vb + w * 16 + c) * D + (h) * 32 + q * 8;\
        float4 u0 = *reinterpret_cast<const float4*>(xr);                      \
        float4 u1 = *reinterpret_cast<const float4*>(xr + 4);                  \
        float f[8] = {u0.x, u0.y, u0.z, u0.w, u1.x, u1.y, u1.z, u1.w};         \
        s16x8 hiv, lov;                                                        \
        _Pragma("unroll") for (int j = 0; j < 8; ++j) {                        \
            unsigned short hb = bf16_rne(f[j]);                                \
            hiv[j] = (short)hb;                                                \
            lov[j] = (short)bf16_rne(f[j] - bf16_f32(hb));                     \
        }                                                                      \
        AH = hiv; AL = lov;                                                    \
    }
    LOAD_A(0, Ah0, Al0)
    LOAD_A(1, Ah1, Al1)
#undef LOAD_A

    // ---- prologue: DMA tile 0's chunks (wave w -> chunks w*4..w*4+3) ----
    {
        const char* gbase = (const char*)ep4 + (size_t)(w * 4) * 1024 + lane * 16;
        char* lbase = (char*)bt[0] + (w * 4) * 1024;
#pragma unroll
        for (int i = 0; i < 4; ++i)
            async_load16(gbase + i * 1024, lbase + i * 1024);
    }

    float best[4];
    int   bk_[4];
#pragma unroll
    for (int s = 0; s < 4; ++s) { best[s] = -3.4e38f; bk_[s] = 0; }

    for (int ct = 0; ct < 16; ++ct) {
        __syncthreads();   // vmcnt(0)+barrier: tile ct ready in bt[ct&1];
                           // everyone done reading bt[(ct+1)&1]

        if (ct < 15) {     // DMA next tile into the other buffer
            const char* gbase = (const char*)ep4
                + (size_t)((ct + 1) * 16 + w * 4) * 1024 + lane * 16;
            char* lbase = (char*)bt[(ct + 1) & 1] + (w * 4) * 1024;
#pragma unroll
            for (int i = 0; i < 4; ++i)
                async_load16(gbase + i * 1024, lbase + i * 1024);
        }

        const unsigned short* bufS = bt[ct & 1];
#pragma unroll
        for (int g = 0; g < 4; ++g) {
            // canonical conflict-free b128 reads: chunk*512 shorts + lane*8
            s16x8 Bh0 = *reinterpret_cast<const s16x8*>(bufS + (g * 4 + 0) * 512 + lane * 8);
            s16x8 Bh1 = *reinterpret_cast<const s16x8*>(bufS + (g * 4 + 1) * 512 + lane * 8);
            s16x8 Bl0 = *reinterpret_cast<const s16x8*>(bufS + (g * 4 + 2) * 512 + lane * 8);
            s16x8 Bl1 = *reinterpret_cast<const s16x8*>(bufS + (g * 4 + 3) * 512 + lane * 8);

            const int codeG = ct * 64 + g * 16 + c;
            const float e2 = -0.5f * en[codeG];
            f32x4 acc = (f32x4){e2, e2, e2, e2};   // fold -enc/2 into C operand

            acc = MFMA(Ah0, Bh0, acc);
            acc = MFMA(Ah1, Bh1, acc);
            acc = MFMA(Ah0, Bl0, acc);
            acc = MFMA(Ah1, Bl1, acc);
            acc = MFMA(Al0, Bh0, acc);
            acc = MFMA(Al1, Bh1, acc);

            // score = dot - enc/2; argMAX(score) == argMIN(dist), exact ties
#pragma unroll
            for (int r = 0; r < 4; ++r) {
                if (acc[r] > best[r]) { best[r] = acc[r]; bk_[r] = codeG; }
            }
        }
    }

    // ---- reduce over the 16 code-columns (max score; tie -> smaller idx) ----
#pragma unroll
    for (int m = 1; m <= 8; m <<= 1)
#pragma unroll
        for (int s = 0; s < 4; ++s) {
            float ob = __shfl_xor(best[s], m, 64);
            int   ok = __shfl_xor(bk_[s], m, 64);
            if (ob > best[s] || (ob == best[s] && ok < bk_[s])) {
                best[s] = ob; bk_[s] = ok;
            }
        }
    if (c == 0) {
#pragma unroll
        for (int r = 0; r < 4; ++r) {
            int lv = w * 16 + q * 4 + r;
            int kk = bk_[r];
            bks[lv] = kk;
            atomicAdd(&counts[kk], 1);
        }
    }
    __syncthreads();

    // ---- gather winning rows -> out (exact fp32) ----
    {
        int vec = t >> 2, part = t & 3;
        int kk = bks[vec];
        const float4* src = reinterpret_cast<const float4*>(emb + (size_t)kk * D) + part * 4;
        float4* dst = reinterpret_cast<float4*>(out + (size_t)(vb + vec) * D) + part * 4;
#pragma unroll
        for (int j = 0; j < 4; ++j) dst[j] = src[j];
    }
}

// ---------------------------------------------------------------------------
// Kernel C: perplexity = exp(-sum p log(p+eps)), p = counts/N. 256 threads.
// ---------------------------------------------------------------------------
__global__ void perplexity_kernel(const int* __restrict__ counts,
                                  float* __restrict__ outp) {
    int t = threadIdx.x;
    float s = 0.f;
#pragma unroll
    for (int i = 0; i < 4; ++i) {
        float p = (float)counts[t + i * 256] * (1.0f / (float)N_VEC);
        s += p * logf(p + VQ_EPS);
    }
#pragma unroll
    for (int m = 1; m < 64; m <<= 1) s += __shfl_xor(s, m, 64);
    __shared__ float ws[4];
    if ((t & 63) == 0) ws[t >> 6] = s;
    __syncthreads();
    if (t == 0) *outp = expf(-(ws[0] + ws[1] + ws[2] + ws[3]));
}

// ---------------------------------------------------------------------------
extern "C" void kernel_launch(void* const* d_in, const int* in_sizes, int n_in,
                              void* d_out, int out_size, void* d_ws, size_t ws_size,
                              hipStream_t stream) {
    const float* x   = (const float*)d_in[0];   // [65536, 64] fp32
    const float* emb = (const float*)d_in[1];   // [1024, 64] fp32
    float* out = (float*)d_out;                 // 4194304 quantized + 1 perplexity

    uint4* ep     = (uint4*)d_ws;                                      // 256 KB packed
    float* enorm  = (float*)((char*)d_ws + (size_t)K * 128 * 2);       // 4 KB
    int*   counts = (int*)((char*)enorm + K * sizeof(float));          // 4 KB

    pack_e_kernel<<<16, 256, 0, stream>>>(emb, ep, enorm, counts);
    vq_kernel<<<N_VEC / 64, 256, 0, stream>>>(x, emb, ep, enorm, counts, out);
    perplexity_kernel<<<1, 256, 0, stream>>>(counts, out + (size_t)N_VEC * D);
}